// Round 6
// baseline (722.211 us; speedup 1.0000x reference)
//
#include <hip/hip_runtime.h>

#define M_ROWS 8192
#define DIN    4096
#define DOUT   4096
#define RANK   32
#define KAUG   4128   // DIN + RANK (valid data)
#define KPAD   4160   // 65*64: K padded to multiple of BK=64; pad zeroed
#define KTILES 65
#define ROWS_PB 4     // rows per block in rot_quant role
#define NROTB  (M_ROWS / ROWS_PB)   // 2048 rot blocks

typedef __attribute__((ext_vector_type(8))) short short8;
typedef __attribute__((ext_vector_type(4))) float floatx4;

__device__ __forceinline__ unsigned short f2bf(float f) {
    unsigned int u = __float_as_uint(f);
    unsigned int r = (u + 0x7FFFu + ((u >> 16) & 1u)) >> 16;  // RNE
    return (unsigned short)r;
}

// ---------------------------------------------------------------------------
// Kernel 1 (fused prep): blocks [0,2048) = rot_quant role (4 rows each),
// blocks [2048,6144) = cast_w role. Block-uniform branch.
// ---------------------------------------------------------------------------
__global__ __launch_bounds__(256) void prep_kernel(
    const float* __restrict__ x, const float* __restrict__ sgn,
    const float* __restrict__ lora_a,
    const float* __restrict__ w, const float* __restrict__ lora_b,
    unsigned short* __restrict__ xaug, unsigned short* __restrict__ waug)
{
    __shared__ unsigned short xrot[ROWS_PB][DIN];   // 32 KiB bf16 x_rot
    __shared__ float tred[ROWS_PB][RANK][8];        // 4 KiB partials

    const int t = threadIdx.x;

    if (blockIdx.x >= NROTB) {
        // ---- cast_w role ----
        const int n = blockIdx.x - NROTB;
        unsigned short* wr = waug + (size_t)n * KPAD;
        const float* wsrc = w + (size_t)n * DIN;
        #pragma unroll
        for (int it = 0; it < 2; ++it) {
            const int base = (it * 256 + t) * 8;
            float4 a = ((const float4*)wsrc)[base >> 2];
            float4 b = ((const float4*)wsrc)[(base >> 2) + 1];
            unsigned int p0 = (unsigned int)f2bf(a.x) | ((unsigned int)f2bf(a.y) << 16);
            unsigned int p1 = (unsigned int)f2bf(a.z) | ((unsigned int)f2bf(a.w) << 16);
            unsigned int p2 = (unsigned int)f2bf(b.x) | ((unsigned int)f2bf(b.y) << 16);
            unsigned int p3 = (unsigned int)f2bf(b.z) | ((unsigned int)f2bf(b.w) << 16);
            *(uint4*)(wr + base) = make_uint4(p0, p1, p2, p3);
        }
        if (t < RANK)
            wr[DIN + t] = f2bf(lora_b[(size_t)n * RANK + t]);
        if (t < 4)
            *(uint4*)&wr[KAUG + t * 8] = make_uint4(0, 0, 0, 0);
        return;
    }

    // ---- rot_quant role ----
    const int row0 = blockIdx.x * ROWS_PB;
    const float inv = 0.08838834764831845f;  // 1/sqrt(128)

    float sg[16];
    #pragma unroll
    for (int q = 0; q < 4; ++q)
        *(float4*)&sg[4 * q] = ((const float4*)sgn)[t * 4 + q];

    // zero the K padding [4128,4160)
    if (t < ROWS_PB * 4) {
        const int rr = t >> 2, q = t & 3;
        *(uint4*)&xaug[(size_t)(row0 + rr) * KPAD + KAUG + q * 8] =
            make_uint4(0, 0, 0, 0);
    }

    #pragma unroll 1
    for (int rr = 0; rr < ROWS_PB; ++rr) {
        const float* xr = x + (size_t)(row0 + rr) * DIN;
        float v[16];
        #pragma unroll
        for (int q = 0; q < 4; ++q)
            *(float4*)&v[4 * q] = ((const float4*)xr)[t * 4 + q];
        #pragma unroll
        for (int j = 0; j < 16; ++j) v[j] *= sg[j];

        // FWHT h=1,2,4,8 in-register
        #pragma unroll
        for (int h = 1; h < 16; h <<= 1) {
            #pragma unroll
            for (int i = 0; i < 16; ++i) {
                if (!(i & h)) {
                    float a = v[i], b = v[i + h];
                    v[i] = a + b;
                    v[i + h] = a - b;
                }
            }
        }
        // FWHT h=16,32,64 via shfl_xor in 8-lane groups
        #pragma unroll
        for (int m = 1; m <= 4; m <<= 1) {
            const bool up = (t & m) != 0;
            #pragma unroll
            for (int j = 0; j < 16; ++j) {
                float o = __shfl_xor(v[j], m, 64);
                v[j] = up ? (o - v[j]) : (v[j] + o);
            }
        }
        #pragma unroll
        for (int j = 0; j < 16; ++j) v[j] *= inv;

        // park x_rot bf16 in LDS
        {
            unsigned int xp[8];
            #pragma unroll
            for (int j = 0; j < 8; ++j)
                xp[j] = (unsigned int)f2bf(v[2 * j]) |
                        ((unsigned int)f2bf(v[2 * j + 1]) << 16);
            *(uint4*)&xrot[rr][16 * t]     = make_uint4(xp[0], xp[1], xp[2], xp[3]);
            *(uint4*)&xrot[rr][16 * t + 8] = make_uint4(xp[4], xp[5], xp[6], xp[7]);
        }

        // NVFP4 fake-quant -> bf16 Xaug
        {
            float amax = 0.f;
            #pragma unroll
            for (int j = 0; j < 16; ++j) amax = fmaxf(amax, fabsf(v[j]));
            amax = fmaxf(amax, 1e-12f);
            float scale = amax / 6.0f;
            unsigned int pk[8];
            #pragma unroll
            for (int j = 0; j < 8; ++j) {
                unsigned short q2[2];
                #pragma unroll
                for (int e = 0; e < 2; ++e) {
                    float vv = v[2 * j + e];
                    float an = fabsf(vv) / scale;
                    float lev = 0.0f;
                    lev = an > 0.25f ? 0.5f : lev;
                    lev = an > 0.75f ? 1.0f : lev;
                    lev = an > 1.25f ? 1.5f : lev;
                    lev = an > 1.75f ? 2.0f : lev;
                    lev = an > 2.5f  ? 3.0f : lev;
                    lev = an > 3.5f  ? 4.0f : lev;
                    lev = an > 5.0f  ? 6.0f : lev;
                    q2[e] = f2bf(copysignf(lev * scale, vv));
                }
                pk[j] = (unsigned int)q2[0] | ((unsigned int)q2[1] << 16);
            }
            unsigned short* orow = xaug + (size_t)(row0 + rr) * KPAD + 16 * t;
            ((uint4*)orow)[0] = make_uint4(pk[0], pk[1], pk[2], pk[3]);
            ((uint4*)orow)[1] = make_uint4(pk[4], pk[5], pk[6], pk[7]);
        }
    }
    __syncthreads();

    // LoRA T: thread=(r=t>>3, c=t&7), rotated start for conflict-free LDS
    {
        const int r = t >> 3, c = t & 7;
        const float* ar = lora_a + (size_t)r * DIN;
        float acc4[ROWS_PB] = {0.f, 0.f, 0.f, 0.f};
        #pragma unroll 1
        for (int i = 0; i < 64; ++i) {
            const int d = (c << 9) + (((i << 3) + (c << 3)) & 511);
            float4 a0 = *(const float4*)(ar + d);
            float4 a1 = *(const float4*)(ar + d + 4);
            #pragma unroll
            for (int rr = 0; rr < ROWS_PB; ++rr) {
                uint4 xb = *(const uint4*)&xrot[rr][d];
                float x0 = __uint_as_float(xb.x << 16);
                float x1 = __uint_as_float(xb.x & 0xFFFF0000u);
                float x2 = __uint_as_float(xb.y << 16);
                float x3 = __uint_as_float(xb.y & 0xFFFF0000u);
                float x4 = __uint_as_float(xb.z << 16);
                float x5 = __uint_as_float(xb.z & 0xFFFF0000u);
                float x6 = __uint_as_float(xb.w << 16);
                float x7 = __uint_as_float(xb.w & 0xFFFF0000u);
                acc4[rr] += a0.x * x0 + a0.y * x1 + a0.z * x2 + a0.w * x3 +
                            a1.x * x4 + a1.y * x5 + a1.z * x6 + a1.w * x7;
            }
        }
        #pragma unroll
        for (int rr = 0; rr < ROWS_PB; ++rr) tred[rr][r][c] = acc4[rr];
    }
    __syncthreads();
    if (t < ROWS_PB * RANK) {
        const int rr = t >> 5, rk = t & 31;
        float s = 0.f;
        #pragma unroll
        for (int k = 0; k < 8; ++k) s += tred[rr][rk][k];
        xaug[(size_t)(row0 + rr) * KPAD + DIN + rk] = f2bf(s);
    }
}

// ---------------------------------------------------------------------------
// Kernel 2: 256x256 GEMM. r6 change: FRAGMENT DOUBLE-BUFFERING — each phase's
// MFMA cluster consumes fragments ds_read in the PREVIOUS phase; this phase's
// ds_reads (next cluster's frags) issue after barrier1 and drain on the LDS
// pipe DURING the MFMA cluster. Removes the per-phase [LDS drain]->[MFMA]
// serialization that capped MfmaUtil at ~43% (r4/r5: conflict fix 2.6e7->0
// moved util only 42->43.7 => drain epochs, not conflicts, were the wall).
// Prefetch chain per K-tile (buf b, staging into nb=b^1):
//   pro: afX<-b.kh0.mi0-3, bf0<-b.kh0
//   P0: STG A-kh0->nb | bar | afY<-b.kh0.mi4-7       | MFMA(afX,bf0->accLo)
//   P1: STG B-kh0->nb, vmcnt(4) | bar | afX<-b.kh1.mi0-3, bf1<-b.kh1
//                                                    | MFMA(afY,bf0->accHi)
//   P2: STG A-kh1->nb | bar | afY<-b.kh1.mi4-7       | MFMA(afX,bf1->accLo)
//   P3: STG B-kh1->nb, vmcnt(4) | bar | afX<-nb.kh0.mi0-3, bf0<-nb.kh0
//                                                    | MFMA(afY,bf1->accHi)
// P3's cross-buffer prefetch is safe: its vmcnt(4) drains exactly the A-kh0/
// B-kh0 stages of nb; barrier makes them cross-wave visible before the reads.
// ---------------------------------------------------------------------------
__global__ __launch_bounds__(512) void gemm_kernel(
    const unsigned short* __restrict__ A,   // [8192][4160] bf16 bits
    const unsigned short* __restrict__ Bm,  // [4096][4160] bf16 bits
    const float* __restrict__ bias,
    float* __restrict__ C)                  // [8192][4096]
{
    __shared__ unsigned short As[2][2][8192];   // [buf][kh][16 KiB]
    __shared__ unsigned short Bs[2][2][8192];

    const int bid = blockIdx.x;
    const int mt = bid >> 4, nt = bid & 15;      // 32 x 16 tiles
    const int m0 = mt * 256, n0 = nt * 256;
    const int t = threadIdx.x;
    const int wave = t >> 6, lane = t & 63;
    const int wm = wave >> 2, wn = wave & 3;     // wave tile 128x64
    const int lm = lane & 15, lq = lane >> 4;

    // staging: chunk = 16 rows x 32 cols (1 KiB), LDS linear.
    // lane l -> LDS row pr=l>>2, LDS slot l&3; GLOBAL slot = (l&3)^((pr>>1)&3).
    const int pr = lane >> 2;
    const int sgs = (lane & 3) ^ ((pr >> 1) & 3);
    const int cc0 = wave * 2, cc1 = wave * 2 + 1;   // this wave's chunks

    // read: row lm, LDS slot lq^((lm>>1)&3) -> global slot lq (conflict-free)
    const int rdo = lm * 64 + ((lq ^ ((lm >> 1) & 3)) << 4);

#define STG(MAT, RB, DST, KT, KH, CC) do {                                    \
    const unsigned short* g_ = (MAT) + (size_t)((RB) + (CC) * 16 + pr) * KPAD \
                               + (KT) * 64 + (KH) * 32 + sgs * 8;             \
    __builtin_amdgcn_global_load_lds(                                         \
        (const __attribute__((address_space(1))) void*)g_,                    \
        (__attribute__((address_space(3))) void*)((DST) + (CC) * 512),        \
        16, 0, 0); } while (0)

// fragment reads: AD/BD = LDS half base (char*), MI0 = first of 4 m-frags
#define RD_A(DSTF, AD, MI0) do {                                              \
    _Pragma("unroll")                                                         \
    for (int i_ = 0; i_ < 4; ++i_)                                            \
        DSTF[i_] = *(const short8*)((AD) + (wm * 8 + (MI0) + i_) * 1024 + rdo); \
    } while (0)
#define RD_B(DSTF, BD) do {                                                   \
    _Pragma("unroll")                                                         \
    for (int j_ = 0; j_ < 4; ++j_)                                            \
        DSTF[j_] = *(const short8*)((BD) + (wn * 4 + j_) * 1024 + rdo);       \
    } while (0)

// MFMA cluster: 4x4 frags into acc rows [AO, AO+4)
#define MM(AO, AF, BF) do {                                                   \
    __builtin_amdgcn_s_setprio(1);                                            \
    _Pragma("unroll")                                                         \
    for (int i_ = 0; i_ < 4; ++i_)                                            \
        _Pragma("unroll")                                                     \
        for (int j_ = 0; j_ < 4; ++j_)                                        \
            acc[(AO) + i_][j_] = __builtin_amdgcn_mfma_f32_16x16x32_bf16(     \
                AF[i_], BF[j_], acc[(AO) + i_][j_], 0, 0, 0);                 \
    __builtin_amdgcn_s_setprio(0);                                            \
    } while (0)

#define SBAR __builtin_amdgcn_sched_barrier(0)

    floatx4 acc[8][4] = {};
    short8 afX[4], afY[4], bf0[4], bf1[4];

    // prologue: stage tile 0 in consumption order, keep kh1 in flight
    STG(A,  m0, &As[0][0][0], 0, 0, cc0); STG(A,  m0, &As[0][0][0], 0, 0, cc1);
    STG(Bm, n0, &Bs[0][0][0], 0, 0, cc0); STG(Bm, n0, &Bs[0][0][0], 0, 0, cc1);
    STG(A,  m0, &As[0][1][0], 0, 1, cc0); STG(A,  m0, &As[0][1][0], 0, 1, cc1);
    STG(Bm, n0, &Bs[0][1][0], 0, 1, cc0); STG(Bm, n0, &Bs[0][1][0], 0, 1, cc1);
    asm volatile("s_waitcnt vmcnt(4)" ::: "memory");
    __builtin_amdgcn_s_barrier();
    RD_A(afX, (const char*)&As[0][0][0], 0);
    RD_B(bf0, (const char*)&Bs[0][0][0]);

    #pragma unroll 1
    for (int kt = 0; kt < KTILES; ++kt) {
        const int b = kt & 1;
        const bool st = (kt + 1 < KTILES);
        const char* a0c = (const char*)&As[b][0][0];
        const char* a1c = (const char*)&As[b][1][0];
        const char* b1c = (const char*)&Bs[b][1][0];
        const char* na0 = (const char*)&As[b ^ 1][0][0];
        const char* nb0 = (const char*)&Bs[b ^ 1][0][0];
        unsigned short* nA0 = &As[b ^ 1][0][0];
        unsigned short* nA1 = &As[b ^ 1][1][0];
        unsigned short* nB0 = &Bs[b ^ 1][0][0];
        unsigned short* nB1 = &Bs[b ^ 1][1][0];

        // ---- P0: stage A-kh0' ; prefetch afY(kh0 mi4-7) ; MFMA(afX,bf0->lo)
        if (st) { STG(A, m0, nA0, kt + 1, 0, cc0); STG(A, m0, nA0, kt + 1, 0, cc1); }
        SBAR; __builtin_amdgcn_s_barrier(); SBAR;
        RD_A(afY, a0c, 4);
        SBAR;
        MM(0, afX, bf0);
        SBAR; __builtin_amdgcn_s_barrier();

        // ---- P1: stage B-kh0' + vmcnt(4) ; prefetch afX,bf1(kh1) ; MFMA(afY,bf0->hi)
        if (st) {
            STG(Bm, n0, nB0, kt + 1, 0, cc0); STG(Bm, n0, nB0, kt + 1, 0, cc1);
            asm volatile("s_waitcnt vmcnt(4)" ::: "memory");
        } else {
            asm volatile("s_waitcnt vmcnt(0)" ::: "memory");
        }
        SBAR; __builtin_amdgcn_s_barrier(); SBAR;
        RD_A(afX, a1c, 0);
        RD_B(bf1, b1c);
        SBAR;
        MM(4, afY, bf0);
        SBAR; __builtin_amdgcn_s_barrier();

        // ---- P2: stage A-kh1' ; prefetch afY(kh1 mi4-7) ; MFMA(afX,bf1->lo)
        if (st) { STG(A, m0, nA1, kt + 1, 1, cc0); STG(A, m0, nA1, kt + 1, 1, cc1); }
        SBAR; __builtin_amdgcn_s_barrier(); SBAR;
        RD_A(afY, a1c, 4);
        SBAR;
        MM(0, afX, bf1);
        SBAR; __builtin_amdgcn_s_barrier();

        // ---- P3: stage B-kh1' + vmcnt(4) ; prefetch afX,bf0 from NEXT buf kh0
        if (st) {
            STG(Bm, n0, nB1, kt + 1, 1, cc0); STG(Bm, n0, nB1, kt + 1, 1, cc1);
            asm volatile("s_waitcnt vmcnt(4)" ::: "memory");
        }
        SBAR; __builtin_amdgcn_s_barrier(); SBAR;
        if (st) {
            RD_A(afX, na0, 0);
            RD_B(bf0, nb0);
        }
        SBAR;
        MM(4, afY, bf1);
        SBAR; __builtin_amdgcn_s_barrier();
    }
#undef STG
#undef RD_A
#undef RD_B
#undef MM
#undef SBAR

    // epilogue: += bias, store fp32
    float bv[4];
    #pragma unroll
    for (int j = 0; j < 4; ++j)
        bv[j] = bias[n0 + wn * 64 + j * 16 + lm];
    #pragma unroll
    for (int i = 0; i < 8; ++i) {
        #pragma unroll
        for (int j = 0; j < 4; ++j) {
            const int col = n0 + wn * 64 + j * 16 + lm;
            #pragma unroll
            for (int r = 0; r < 4; ++r) {
                const int row = m0 + wm * 128 + i * 16 + lq * 4 + r;
                C[(size_t)row * DOUT + col] = acc[i][j][r] + bv[j];
            }
        }
    }
}

// ---------------------------------------------------------------------------
extern "C" void kernel_launch(void* const* d_in, const int* in_sizes, int n_in,
                              void* d_out, int out_size, void* d_ws, size_t ws_size,
                              hipStream_t stream) {
    const float* x      = (const float*)d_in[0];
    const float* sgn    = (const float*)d_in[1];
    // d_in[2] = H_block (unused; Sylvester Hadamard via FWHT)
    const float* w      = (const float*)d_in[3];
    const float* lora_a = (const float*)d_in[4];
    const float* lora_b = (const float*)d_in[5];
    const float* bias   = (const float*)d_in[6];
    float* out = (float*)d_out;

    unsigned short* xaug = (unsigned short*)d_ws;                 // [8192][4160] bf16
    unsigned short* waug = xaug + (size_t)M_ROWS * KPAD;          // [4096][4160] bf16

    prep_kernel<<<NROTB + DOUT, 256, 0, stream>>>(x, sgn, lora_a, w, lora_b,
                                                  xaug, waug);
    gemm_kernel<<<(M_ROWS / 256) * (DOUT / 256), 512, 0, stream>>>(xaug, waug, bias, out);
}